// Round 1
// baseline (1943.419 us; speedup 1.0000x reference)
//
#include <hip/hip_runtime.h>
#include <hip/hip_bf16.h>

#define NB 8
#define NG 8
#define NT 4096
#define NDIM 1024
#define NGD 128
#define NATT 128
#define NKL 256
#define FSCALE 0.08838834764831845f  // 1/sqrt(128)

// ---------------------------------------------------------------------------
// K0: Wvo[g] = Wv[g] @ Wo[g]   (fold output projection into v-path weights)
// grid: 8 blocks x 256 threads. Trivial cost.
// ---------------------------------------------------------------------------
__global__ __launch_bounds__(256) void k0_wvo(const float* __restrict__ Wv,
                                              const float* __restrict__ Wo,
                                              float* __restrict__ Wvo) {
  const int g = blockIdx.x;
  __shared__ float wv[NGD * NGD];
  for (int i = threadIdx.x; i < NGD * NGD; i += 256) wv[i] = Wv[g * NGD * NGD + i];
  __syncthreads();
  const int d = threadIdx.x >> 1;          // row of Wvo
  const int f0 = (threadIdx.x & 1) * 64;   // col half
  float acc[64];
#pragma unroll
  for (int j = 0; j < 64; ++j) acc[j] = 0.f;
  const float* wo = Wo + g * NGD * NGD + f0;
  for (int e = 0; e < NGD; ++e) {
    const float a = wv[d * NGD + e];
    const float* wr = wo + e * NGD;
#pragma unroll 16
    for (int j = 0; j < 64; ++j) acc[j] += a * wr[j];
  }
  float* o = Wvo + g * NGD * NGD + d * NGD + f0;
#pragma unroll
  for (int j = 0; j < 64; ++j) o[j] = acc[j];
}

// ---------------------------------------------------------------------------
// K1: sel=0: k_red[bg]  = (Pk[g]^T @ xg[b,g]) @ Wk[g]    [256 x 128]
//     sel=1: vo_red[bg] = (Pv[g]^T @ xg[b,g]) @ Wvo[g]   [256 x 128]
// One block computes a 128(kl) x 128(d) tile of P^T@X (K = T = 4096), then
// applies the 128x128 weight via an LDS round-trip.
// grid: (KL/128=2, 2, B*G=64), 256 threads, 67.6 KB LDS.
// ---------------------------------------------------------------------------
__global__ __launch_bounds__(256) void k1_reduce(
    const float* __restrict__ x, const float* __restrict__ Pk,
    const float* __restrict__ Pv, const float* __restrict__ Wk,
    const float* __restrict__ Wvo, float* __restrict__ k_red,
    float* __restrict__ vo_red) {
  const int klt = blockIdx.x;  // 0..1
  const int sel = blockIdx.y;  // 0=k path, 1=v path
  const int bg = blockIdx.z;
  const int b = bg >> 3, g = bg & 7;
  const float* P = (sel ? Pv : Pk) + (size_t)g * NT * NKL + klt * 128;
  const float* W = (sel ? Wvo : Wk) + (size_t)g * NGD * NATT;
  float* outp = (sel ? vo_red : k_red) + ((size_t)bg * NKL + klt * 128) * NATT;
  const float* xb = x + (size_t)b * NT * NDIM + g * NGD;

  __shared__ float smem[128 * 132];  // phase A: pt[32][132] + xt[32][132]; phase B: C[128][132]
  float* pt = smem;
  float* xt = smem + 32 * 132;

  const int tid = threadIdx.x;
  const int mr = tid >> 4;          // 0..15 : kl rows mr*8..+7
  const int mc = tid & 15;          // 0..15 : d cols mc*8..+7
  const int lrow = tid >> 3;        // 0..31 loader row
  const int lc16 = (tid & 7) * 16;  // loader col

  float acc[8][8];
#pragma unroll
  for (int i = 0; i < 8; ++i)
#pragma unroll
    for (int j = 0; j < 8; ++j) acc[i][j] = 0.f;

  for (int t0 = 0; t0 < NT; t0 += 32) {
    __syncthreads();
    const float* pr = P + (size_t)(t0 + lrow) * NKL + lc16;
    const float* xr = xb + (size_t)(t0 + lrow) * NDIM + lc16;
#pragma unroll
    for (int u = 0; u < 4; ++u) {
      *(float4*)&pt[lrow * 132 + lc16 + u * 4] = *(const float4*)(pr + u * 4);
      *(float4*)&xt[lrow * 132 + lc16 + u * 4] = *(const float4*)(xr + u * 4);
    }
    __syncthreads();
    for (int t = 0; t < 32; ++t) {
      float xv[8], pv[8];
      *(float4*)&xv[0] = *(const float4*)&xt[t * 132 + mc * 8];
      *(float4*)&xv[4] = *(const float4*)&xt[t * 132 + mc * 8 + 4];
#pragma unroll
      for (int i = 0; i < 8; ++i) pv[i] = pt[t * 132 + mr * 8 + i];
#pragma unroll
      for (int i = 0; i < 8; ++i)
#pragma unroll
        for (int j = 0; j < 8; ++j) acc[i][j] += pv[i] * xv[j];
    }
  }
  // stage C = P^T@X tile into LDS, then O = C @ W
  __syncthreads();
#pragma unroll
  for (int i = 0; i < 8; ++i) {
    *(float4*)&smem[(mr * 8 + i) * 132 + mc * 8] =
        make_float4(acc[i][0], acc[i][1], acc[i][2], acc[i][3]);
    *(float4*)&smem[(mr * 8 + i) * 132 + mc * 8 + 4] =
        make_float4(acc[i][4], acc[i][5], acc[i][6], acc[i][7]);
  }
  __syncthreads();
  float o[8][8];
#pragma unroll
  for (int i = 0; i < 8; ++i)
#pragma unroll
    for (int j = 0; j < 8; ++j) o[i][j] = 0.f;
  for (int dd = 0; dd < NGD; ++dd) {
    float w[8], c[8];
    *(float4*)&w[0] = *(const float4*)&W[(size_t)dd * NATT + mc * 8];
    *(float4*)&w[4] = *(const float4*)&W[(size_t)dd * NATT + mc * 8 + 4];
#pragma unroll
    for (int i = 0; i < 8; ++i) c[i] = smem[(mr * 8 + i) * 132 + dd];
#pragma unroll
    for (int i = 0; i < 8; ++i)
#pragma unroll
      for (int j = 0; j < 8; ++j) o[i][j] += c[i] * w[j];
  }
#pragma unroll
  for (int i = 0; i < 8; ++i) {
    *(float4*)&outp[(size_t)(mr * 8 + i) * NATT + mc * 8] =
        make_float4(o[i][0], o[i][1], o[i][2], o[i][3]);
    *(float4*)&outp[(size_t)(mr * 8 + i) * NATT + mc * 8 + 4] =
        make_float4(o[i][4], o[i][5], o[i][6], o[i][7]);
  }
}

// ---------------------------------------------------------------------------
// K2: fused attention per 64-row t-tile of one (b,g):
//   q = x_tile @ Wq; s = q @ k_red^T * SCALE; att = softmax(s);
//   out = att @ vo_red   (Wo already folded into vo_red)
// grid: (T/64=64, B*G=64), 512 threads, 99 KB LDS.
// scores live in registers (4 rows x 8 strided cols per thread); row softmax
// reduces across a contiguous half-wave via __shfl_xor width 32.
// ---------------------------------------------------------------------------
__global__ __launch_bounds__(512) void k2_attn(
    const float* __restrict__ x, const float* __restrict__ Wq,
    const float* __restrict__ k_red, const float* __restrict__ vo_red,
    float* __restrict__ out) {
  const int tt = blockIdx.x;
  const int bg = blockIdx.y;
  const int b = bg >> 3, g = bg & 7;
  const int t0 = tt * 64;

  __shared__ float smem[25344];  // 99 KB
  float* qs = smem;                                       // [64][132] fp32
  float* ck = smem + 64 * 132;                            // [64][132] staging
  __hip_bfloat16* att = (__hip_bfloat16*)(smem + 2 * 64 * 132);  // [64][264] bf16

  const int tid = threadIdx.x;
  const int mi = tid >> 5;          // 0..15 : rows mi*4..+3
  const int mj = tid & 31;          // 0..31
  const int lrow = tid >> 3;        // 0..63 loader row
  const int lc16 = (tid & 7) * 16;

  const float* xb = x + ((size_t)b * NT + t0) * NDIM + g * NGD;

  // ---- phase 1: stage x tile, compute q = x @ Wq into LDS ----
  {
    const float* xr = xb + (size_t)lrow * NDIM + lc16;
#pragma unroll
    for (int u = 0; u < 4; ++u)
      *(float4*)&ck[lrow * 132 + lc16 + u * 4] = *(const float4*)(xr + u * 4);
  }
  __syncthreads();
  {
    const float* wq = Wq + (size_t)g * NGD * NATT + mj * 4;
    float qa[4][4];
#pragma unroll
    for (int i = 0; i < 4; ++i)
#pragma unroll
      for (int j = 0; j < 4; ++j) qa[i][j] = 0.f;
    for (int d = 0; d < NGD; ++d) {
      const float4 w = *(const float4*)(wq + (size_t)d * NATT);
#pragma unroll
      for (int i = 0; i < 4; ++i) {
        const float xv = ck[(mi * 4 + i) * 132 + d];
        qa[i][0] += xv * w.x; qa[i][1] += xv * w.y;
        qa[i][2] += xv * w.z; qa[i][3] += xv * w.w;
      }
    }
#pragma unroll
    for (int i = 0; i < 4; ++i)
      *(float4*)&qs[(mi * 4 + i) * 132 + mj * 4] =
          make_float4(qa[i][0], qa[i][1], qa[i][2], qa[i][3]);
  }

  // ---- phase 2: scores sc[i][jj] for row mi*4+i, col jj*32+mj ----
  float sc[4][8];
#pragma unroll
  for (int i = 0; i < 4; ++i)
#pragma unroll
    for (int jj = 0; jj < 8; ++jj) sc[i][jj] = 0.f;
  const float* kr = k_red + (size_t)bg * NKL * NATT;
  for (int c = 0; c < 4; ++c) {  // 64-key chunks
    __syncthreads();
    const float* krr = kr + (size_t)(c * 64 + lrow) * NATT + lc16;
#pragma unroll
    for (int u = 0; u < 4; ++u)
      *(float4*)&ck[lrow * 132 + lc16 + u * 4] = *(const float4*)(krr + u * 4);
    __syncthreads();
    for (int a0 = 0; a0 < NATT; a0 += 4) {
      float4 qv[4];
#pragma unroll
      for (int i = 0; i < 4; ++i)
        qv[i] = *(const float4*)&qs[(mi * 4 + i) * 132 + a0];
#pragma unroll
      for (int jj2 = 0; jj2 < 2; ++jj2) {
        const float4 kv = *(const float4*)&ck[(jj2 * 32 + mj) * 132 + a0];
#pragma unroll
        for (int i = 0; i < 4; ++i)
          sc[i][c * 2 + jj2] +=
              qv[i].x * kv.x + qv[i].y * kv.y + qv[i].z * kv.z + qv[i].w * kv.w;
      }
    }
  }

  // ---- phase 3: softmax in registers; write att (bf16) to LDS ----
#pragma unroll
  for (int i = 0; i < 4; ++i) {
    float m = -1e30f;
#pragma unroll
    for (int jj = 0; jj < 8; ++jj) {
      sc[i][jj] *= FSCALE;
      m = fmaxf(m, sc[i][jj]);
    }
#pragma unroll
    for (int off = 16; off; off >>= 1) m = fmaxf(m, __shfl_xor(m, off, 32));
    float s = 0.f;
#pragma unroll
    for (int jj = 0; jj < 8; ++jj) {
      const float p = __expf(sc[i][jj] - m);
      sc[i][jj] = p;
      s += p;
    }
#pragma unroll
    for (int off = 16; off; off >>= 1) s += __shfl_xor(s, off, 32);
    const float inv = 1.f / s;
#pragma unroll
    for (int jj = 0; jj < 8; ++jj)
      att[(mi * 4 + i) * 264 + jj * 32 + mj] = __float2bfloat16(sc[i][jj] * inv);
  }

  // ---- phase 4: out = att @ vo_red ----
  float oa[4][4];
#pragma unroll
  for (int i = 0; i < 4; ++i)
#pragma unroll
    for (int j = 0; j < 4; ++j) oa[i][j] = 0.f;
  const float* vr = vo_red + (size_t)bg * NKL * NGD;
  for (int c = 0; c < 4; ++c) {
    __syncthreads();
    const float* vrr = vr + (size_t)(c * 64 + lrow) * NGD + lc16;
#pragma unroll
    for (int u = 0; u < 4; ++u)
      *(float4*)&ck[lrow * 132 + lc16 + u * 4] = *(const float4*)(vrr + u * 4);
    __syncthreads();
    for (int k = 0; k < 64; ++k) {
      const float4 vv = *(const float4*)&ck[k * 132 + mj * 4];
#pragma unroll
      for (int i = 0; i < 4; ++i) {
        const float av = __bfloat162float(att[(mi * 4 + i) * 264 + c * 64 + k]);
        oa[i][0] += av * vv.x; oa[i][1] += av * vv.y;
        oa[i][2] += av * vv.z; oa[i][3] += av * vv.w;
      }
    }
  }
  float* ob = out + ((size_t)b * NT + t0) * NDIM + g * NGD;
#pragma unroll
  for (int i = 0; i < 4; ++i)
    *(float4*)&ob[(size_t)(mi * 4 + i) * NDIM + mj * 4] =
        make_float4(oa[i][0], oa[i][1], oa[i][2], oa[i][3]);
}

// ---------------------------------------------------------------------------
extern "C" void kernel_launch(void* const* d_in, const int* in_sizes, int n_in,
                              void* d_out, int out_size, void* d_ws, size_t ws_size,
                              hipStream_t stream) {
  (void)in_sizes; (void)n_in; (void)out_size; (void)ws_size;
  const float* x  = (const float*)d_in[0];
  const float* Wq = (const float*)d_in[1];
  const float* Wk = (const float*)d_in[2];
  const float* Wv = (const float*)d_in[3];
  const float* Wo = (const float*)d_in[4];
  const float* Pk = (const float*)d_in[5];
  const float* Pv = (const float*)d_in[6];
  float* out = (float*)d_out;

  float* ws = (float*)d_ws;
  float* Wvo    = ws;                       // 8*128*128       = 131072 floats
  float* k_red  = Wvo + NG * NGD * NGD;     // 64*256*128      = 2097152 floats
  float* vo_red = k_red + NB * NG * NKL * NATT;  // 2097152 floats (total ~17.3 MB)

  k0_wvo<<<dim3(NG), dim3(256), 0, stream>>>(Wv, Wo, Wvo);
  k1_reduce<<<dim3(2, 2, NB * NG), dim3(256), 0, stream>>>(x, Pk, Pv, Wk, Wvo,
                                                           k_red, vo_red);
  k2_attn<<<dim3(NT / 64, NB * NG), dim3(512), 0, stream>>>(x, Wq, k_red,
                                                            vo_red, out);
}

// Round 2
// 636.643 us; speedup vs baseline: 3.0526x; 3.0526x over previous
//
#include <hip/hip_runtime.h>
#include <hip/hip_bf16.h>

#define NB 8
#define NG 8
#define NT 4096
#define NDIM 1024
#define NGD 128
#define NATT 128
#define NKL 256
#define FSCALE 0.08838834764831845f  // 1/sqrt(128)

typedef __bf16 bf16x8 __attribute__((ext_vector_type(8)));
typedef float f32x4 __attribute__((ext_vector_type(4)));
typedef ushort u16x8 __attribute__((ext_vector_type(8)));
typedef ushort u16x4 __attribute__((ext_vector_type(4)));

#define MFMA(a, b, c) __builtin_amdgcn_mfma_f32_16x16x32_bf16(a, b, c, 0, 0, 0)

__device__ __forceinline__ ushort f2bf(float f) {  // RNE
  union { float f; unsigned u; } v; v.f = f;
  unsigned r = v.u + 0x7FFFu + ((v.u >> 16) & 1u);
  return (ushort)(r >> 16);
}

// ---------------------------------------------------------------------------
// K0: Wvo = Wv@Wo (fp32) -> WvoT bf16 [att_out][d_in]; WqT/WkT bf16 [att][d].
// ---------------------------------------------------------------------------
__global__ __launch_bounds__(256) void k0_weights(
    const float* __restrict__ Wq, const float* __restrict__ Wk,
    const float* __restrict__ Wv, const float* __restrict__ Wo,
    ushort* __restrict__ WqT, ushort* __restrict__ WkT,
    ushort* __restrict__ WvoT) {
  const int g = blockIdx.x;
  __shared__ float wv[128 * 128];
  for (int i = threadIdx.x; i < 16384; i += 256) wv[i] = Wv[g * 16384 + i];
  __syncthreads();
  const int d = threadIdx.x >> 1;
  const int f0 = (threadIdx.x & 1) * 64;
  float acc[64];
#pragma unroll
  for (int j = 0; j < 64; ++j) acc[j] = 0.f;
  const float* wo = Wo + g * 16384 + f0;
  for (int e = 0; e < 128; ++e) {
    const float a = wv[d * 128 + e];
#pragma unroll 16
    for (int j = 0; j < 64; ++j) acc[j] += a * wo[e * 128 + j];
  }
#pragma unroll
  for (int j = 0; j < 64; ++j)
    WvoT[(size_t)g * 16384 + (size_t)(f0 + j) * 128 + d] = f2bf(acc[j]);
  for (int i = threadIdx.x; i < 16384; i += 256) {
    const int a_ = i >> 7, dd = i & 127;
    WqT[(size_t)g * 16384 + i] = f2bf(Wq[(size_t)g * 16384 + dd * 128 + a_]);
    WkT[(size_t)g * 16384 + i] = f2bf(Wk[(size_t)g * 16384 + dd * 128 + a_]);
  }
}

// ---------------------------------------------------------------------------
// KT_X: xT[bg][d][t] bf16 from x[b][t][g*128+d] fp32. grid (64 tc, 64 bg).
// ---------------------------------------------------------------------------
__global__ __launch_bounds__(256) void kt_x(const float* __restrict__ x,
                                            ushort* __restrict__ xT) {
  const int t0 = blockIdx.x * 64;
  const int bg = blockIdx.y;
  const int b = bg >> 3, g = bg & 7;
  __shared__ float xl[64 * 132];
#pragma unroll
  for (int u = 0; u < 8; ++u) {
    const int c = threadIdx.x + 256 * u;
    const int row = c >> 5, c4 = (c & 31) * 4;
    *(float4*)&xl[row * 132 + c4] =
        *(const float4*)&x[((size_t)b * NT + t0 + row) * NDIM + g * 128 + c4];
  }
  __syncthreads();
  const int d = threadIdx.x >> 1, th = (threadIdx.x & 1) * 32;
  ushort* dst = xT + ((size_t)bg * 128 + d) * NT + t0 + th;
#pragma unroll
  for (int k = 0; k < 8; ++k) {
    u16x4 pk;
#pragma unroll
    for (int z = 0; z < 4; ++z) pk[z] = f2bf(xl[(th + k * 4 + z) * 132 + d]);
    *(u16x4*)&dst[k * 4] = pk;
  }
}

// ---------------------------------------------------------------------------
// KT_P: PT[g][kl][t] bf16 from P[g][t][kl]. grid (64 tc, 2 klh, 8 g).
// ---------------------------------------------------------------------------
__global__ __launch_bounds__(256) void kt_p(const float* __restrict__ P,
                                            ushort* __restrict__ PT) {
  const int t0 = blockIdx.x * 64;
  const int klh = blockIdx.y, g = blockIdx.z;
  __shared__ float pl[64 * 132];
#pragma unroll
  for (int u = 0; u < 8; ++u) {
    const int c = threadIdx.x + 256 * u;
    const int row = c >> 5, c4 = (c & 31) * 4;
    *(float4*)&pl[row * 132 + c4] =
        *(const float4*)&P[((size_t)g * NT + t0 + row) * NKL + klh * 128 + c4];
  }
  __syncthreads();
  const int d = threadIdx.x >> 1, th = (threadIdx.x & 1) * 32;
  ushort* dst = PT + ((size_t)g * NKL + klh * 128 + d) * NT + t0 + th;
#pragma unroll
  for (int k = 0; k < 8; ++k) {
    u16x4 pk;
#pragma unroll
    for (int z = 0; z < 4; ++z) pk[z] = f2bf(pl[(th + k * 4 + z) * 132 + d]);
    *(u16x4*)&dst[k * 4] = pk;
  }
}

// ---------------------------------------------------------------------------
// K1: C1 = P^T@X  (64kl x 128d tile, K=4096, MFMA, reg-staged prefetch), then
//     C2 = C1@W (K=128) fused via LDS. sel=0 -> k_red bf16 [kl][att];
//     sel=1 -> vo_redT bf16 [d][kl]. grid (4 klt, 2 sel, 64 bg), 256 thr.
// ---------------------------------------------------------------------------
__global__ __launch_bounds__(256) void k1_mfma(
    const ushort* __restrict__ PkT, const ushort* __restrict__ PvT,
    const ushort* __restrict__ xT, const ushort* __restrict__ WkT,
    const ushort* __restrict__ WvoT, ushort* __restrict__ k_redb,
    ushort* __restrict__ vo_redT) {
  const int klt = blockIdx.x;
  const int sel = blockIdx.y;
  const int bg = blockIdx.z;
  const int g = bg & 7;
  const ushort* PT = (sel ? PvT : PkT) + ((size_t)g * NKL + klt * 64) * NT;
  const ushort* Xb = xT + (size_t)bg * 128 * NT;

  __shared__ ushort smem[(64 + 128) * 72];  // A[64][72] + B[128][72]; C aliases
  ushort* A = smem;
  ushort* Bs = smem + 64 * 72;
  ushort* C = smem;  // [64][136] = 8704 <= 13824

  const int tid = threadIdx.x;
  const int w = tid >> 6, l = tid & 63, l15 = l & 15, l4 = l >> 4;
  const int ktb = (w & 1) * 2;   // 2 kl-tiles
  const int dtb = (w >> 1) * 4;  // 4 d-tiles

  f32x4 acc[2][4];
  const f32x4 fz = {0.f, 0.f, 0.f, 0.f};
#pragma unroll
  for (int i = 0; i < 2; ++i)
#pragma unroll
    for (int j = 0; j < 4; ++j) acc[i][j] = fz;

  u16x8 ra[2], rb[4];
#pragma unroll
  for (int u = 0; u < 2; ++u) {
    const int c = tid + 256 * u;
    ra[u] = *(const u16x8*)&PT[(size_t)(c >> 3) * NT + (c & 7) * 8];
  }
#pragma unroll
  for (int u = 0; u < 4; ++u) {
    const int c = tid + 256 * u;
    rb[u] = *(const u16x8*)&Xb[(size_t)(c >> 3) * NT + (c & 7) * 8];
  }

  for (int s = 0; s < 64; ++s) {
    __syncthreads();
#pragma unroll
    for (int u = 0; u < 2; ++u) {
      const int c = tid + 256 * u;
      *(u16x8*)&A[(c >> 3) * 72 + (c & 7) * 8] = ra[u];
    }
#pragma unroll
    for (int u = 0; u < 4; ++u) {
      const int c = tid + 256 * u;
      *(u16x8*)&Bs[(c >> 3) * 72 + (c & 7) * 8] = rb[u];
    }
    __syncthreads();
    if (s < 63) {
      const int t0 = (s + 1) * 64;
#pragma unroll
      for (int u = 0; u < 2; ++u) {
        const int c = tid + 256 * u;
        ra[u] = *(const u16x8*)&PT[(size_t)(c >> 3) * NT + t0 + (c & 7) * 8];
      }
#pragma unroll
      for (int u = 0; u < 4; ++u) {
        const int c = tid + 256 * u;
        rb[u] = *(const u16x8*)&Xb[(size_t)(c >> 3) * NT + t0 + (c & 7) * 8];
      }
    }
#pragma unroll
    for (int h = 0; h < 2; ++h) {
      bf16x8 af[2], bfr[4];
#pragma unroll
      for (int i = 0; i < 2; ++i)
        af[i] = *(const bf16x8*)&A[((ktb + i) * 16 + l15) * 72 + h * 32 + l4 * 8];
#pragma unroll
      for (int j = 0; j < 4; ++j)
        bfr[j] = *(const bf16x8*)&Bs[((dtb + j) * 16 + l15) * 72 + h * 32 + l4 * 8];
#pragma unroll
      for (int i = 0; i < 2; ++i)
#pragma unroll
        for (int j = 0; j < 4; ++j) acc[i][j] = MFMA(af[i], bfr[j], acc[i][j]);
    }
  }

  // epilogue: C1 -> LDS bf16 [64][136], then C2 = C1 @ W^T-frags (K=128)
  __syncthreads();
#pragma unroll
  for (int i = 0; i < 2; ++i)
#pragma unroll
    for (int j = 0; j < 4; ++j)
#pragma unroll
      for (int r = 0; r < 4; ++r)
        C[((ktb + i) * 16 + l4 * 4 + r) * 136 + (dtb + j) * 16 + l15] =
            f2bf(acc[i][j][r]);
  __syncthreads();

  const ushort* WT = (sel ? WvoT : WkT) + (size_t)g * 16384;
  f32x4 o[2][4];
#pragma unroll
  for (int i = 0; i < 2; ++i)
#pragma unroll
    for (int j = 0; j < 4; ++j) o[i][j] = fz;
#pragma unroll
  for (int ks = 0; ks < 4; ++ks) {
    bf16x8 af[2], bfr[4];
#pragma unroll
    for (int i = 0; i < 2; ++i)
      af[i] = *(const bf16x8*)&C[((ktb + i) * 16 + l15) * 136 + ks * 32 + l4 * 8];
#pragma unroll
    for (int j = 0; j < 4; ++j)
      bfr[j] = *(const bf16x8*)&WT[(size_t)((dtb + j) * 16 + l15) * 128 + ks * 32 + l4 * 8];
#pragma unroll
    for (int i = 0; i < 2; ++i)
#pragma unroll
      for (int j = 0; j < 4; ++j) o[i][j] = MFMA(af[i], bfr[j], o[i][j]);
  }

  if (sel == 0) {
#pragma unroll
    for (int i = 0; i < 2; ++i)
#pragma unroll
      for (int j = 0; j < 4; ++j)
#pragma unroll
        for (int r = 0; r < 4; ++r)
          k_redb[((size_t)bg * NKL + klt * 64 + (ktb + i) * 16 + l4 * 4 + r) * 128 +
                 (dtb + j) * 16 + l15] = f2bf(o[i][j][r]);
  } else {
#pragma unroll
    for (int i = 0; i < 2; ++i)
#pragma unroll
      for (int j = 0; j < 4; ++j) {
        u16x4 pk;
#pragma unroll
        for (int r = 0; r < 4; ++r) pk[r] = f2bf(o[i][j][r]);
        *(u16x4*)&vo_redT[((size_t)bg * 128 + (dtb + j) * 16 + l15) * NKL +
                          klt * 64 + (ktb + i) * 16 + l4 * 4] = pk;
      }
  }
}

// ---------------------------------------------------------------------------
// K2: per (t-tile 64, bg): q = x@WqT (MFMA, scale folded); S = q@k_red^T;
// wave-parallel softmax (in-reg + shfl16 + LDS pair-combine); PV with
// B-frags direct from vo_redT; 1/sum at C-write. grid (64, 64), 512 thr.
// ---------------------------------------------------------------------------
__global__ __launch_bounds__(512) void k2_attn(
    const float* __restrict__ x, const ushort* __restrict__ WqT,
    const ushort* __restrict__ k_redb, const ushort* __restrict__ vo_redT,
    float* __restrict__ out) {
  const int t0 = blockIdx.x * 64;
  const int bg = blockIdx.y;
  const int b = bg >> 3, g = bg & 7;

  __shared__ ushort smem[64 * 264 + 64 * 136];
  __shared__ float redbuf[256];
  ushort* att = smem;             // [64][264] (aliases x_lds [64][136])
  ushort* xl = smem;
  ushort* ql = smem + 64 * 264;   // [64][136]
  float* mbuf = redbuf;           // [2][64]
  float* sbuf = redbuf + 128;     // [2][64]

  const int tid = threadIdx.x;
  const int w = tid >> 6, l = tid & 63, l15 = l & 15, l4 = l >> 4;
  const int tw = w >> 1, half = w & 1;
  const f32x4 fz = {0.f, 0.f, 0.f, 0.f};

  // phase 0: stage x tile -> bf16 LDS [64][136]
#pragma unroll
  for (int u = 0; u < 4; ++u) {
    const int c = tid + 512 * u;
    const int row = c >> 5, c4 = (c & 31) * 4;
    const float4 f4 =
        *(const float4*)&x[((size_t)b * NT + t0 + row) * NDIM + g * 128 + c4];
    u16x4 pk;
    pk[0] = f2bf(f4.x); pk[1] = f2bf(f4.y); pk[2] = f2bf(f4.z); pk[3] = f2bf(f4.w);
    *(u16x4*)&xl[row * 136 + c4] = pk;
  }
  __syncthreads();

  // phase 1: q = x @ WqT-frags (K=128); write q*SCALE bf16 to ql
  {
    f32x4 qa[4];
#pragma unroll
    for (int j = 0; j < 4; ++j) qa[j] = fz;
#pragma unroll
    for (int ks = 0; ks < 4; ++ks) {
      const bf16x8 a = *(const bf16x8*)&xl[(tw * 16 + l15) * 136 + ks * 32 + l4 * 8];
#pragma unroll
      for (int j = 0; j < 4; ++j) {
        const bf16x8 bv = *(const bf16x8*)&WqT[(size_t)g * 16384 +
            (size_t)((half * 4 + j) * 16 + l15) * 128 + ks * 32 + l4 * 8];
        qa[j] = MFMA(a, bv, qa[j]);
      }
    }
    __syncthreads();  // x reads done everywhere before q-write? (ql separate; but keep order)
#pragma unroll
    for (int j = 0; j < 4; ++j)
#pragma unroll
      for (int r = 0; r < 4; ++r)
        ql[(tw * 16 + l4 * 4 + r) * 136 + (half * 4 + j) * 16 + l15] =
            f2bf(qa[j][r] * FSCALE);
  }
  __syncthreads();

  // phase 2: S = q @ k_red^T ; wave: t-tile tw, kl-tiles half*8+0..7
  f32x4 s[8];
#pragma unroll
  for (int n = 0; n < 8; ++n) s[n] = fz;
  {
    bf16x8 a4[4];
#pragma unroll
    for (int ks = 0; ks < 4; ++ks)
      a4[ks] = *(const bf16x8*)&ql[(tw * 16 + l15) * 136 + ks * 32 + l4 * 8];
#pragma unroll
    for (int n = 0; n < 8; ++n) {
#pragma unroll
      for (int ks = 0; ks < 4; ++ks) {
        const bf16x8 bv = *(const bf16x8*)&k_redb[((size_t)bg * NKL +
            (half * 8 + n) * 16 + l15) * 128 + ks * 32 + l4 * 8];
        s[n] = MFMA(a4[ks], bv, s[n]);
      }
    }
  }

  // phase 3: softmax. rows owned: tw*16 + l4*4 + r
  float inv[4];
  {
    float mx[4];
#pragma unroll
    for (int r = 0; r < 4; ++r) {
      float m = s[0][r];
#pragma unroll
      for (int n = 1; n < 8; ++n) m = fmaxf(m, s[n][r]);
#pragma unroll
      for (int off = 1; off < 16; off <<= 1) m = fmaxf(m, __shfl_xor(m, off, 64));
      mx[r] = m;
    }
    if (l15 == 0) {
#pragma unroll
      for (int r = 0; r < 4; ++r) mbuf[half * 64 + tw * 16 + l4 * 4 + r] = mx[r];
    }
    __syncthreads();
    float sm[4];
#pragma unroll
    for (int r = 0; r < 4; ++r) {
      const float mg = fmaxf(mx[r], mbuf[(half ^ 1) * 64 + tw * 16 + l4 * 4 + r]);
      float acc = 0.f;
#pragma unroll
      for (int n = 0; n < 8; ++n) {
        const float p = __expf(s[n][r] - mg);
        acc += p;
        att[(tw * 16 + l4 * 4 + r) * 264 + (half * 8 + n) * 16 + l15] = f2bf(p);
      }
#pragma unroll
      for (int off = 1; off < 16; off <<= 1) acc += __shfl_xor(acc, off, 64);
      sm[r] = acc;
    }
    if (l15 == 0) {
#pragma unroll
      for (int r = 0; r < 4; ++r) sbuf[half * 64 + tw * 16 + l4 * 4 + r] = sm[r];
    }
    __syncthreads();
#pragma unroll
    for (int r = 0; r < 4; ++r)
      inv[r] = 1.f / (sm[r] + sbuf[(half ^ 1) * 64 + tw * 16 + l4 * 4 + r]);
  }

  // phase 4: O = att @ vo_redT-frags (K=256); d-tiles half*4+0..3
  f32x4 oa[4];
#pragma unroll
  for (int j = 0; j < 4; ++j) oa[j] = fz;
#pragma unroll
  for (int ks = 0; ks < 8; ++ks) {
    const bf16x8 a = *(const bf16x8*)&att[(tw * 16 + l15) * 264 + ks * 32 + l4 * 8];
#pragma unroll
    for (int j = 0; j < 4; ++j) {
      const bf16x8 bv = *(const bf16x8*)&vo_redT[((size_t)bg * 128 +
          (half * 4 + j) * 16 + l15) * NKL + ks * 32 + l4 * 8];
      oa[j] = MFMA(a, bv, oa[j]);
    }
  }
#pragma unroll
  for (int j = 0; j < 4; ++j)
#pragma unroll
    for (int r = 0; r < 4; ++r)
      out[((size_t)b * NT + t0 + tw * 16 + l4 * 4 + r) * NDIM + g * 128 +
          (half * 4 + j) * 16 + l15] = oa[j][r] * inv[r];
}

// ---------------------------------------------------------------------------
extern "C" void kernel_launch(void* const* d_in, const int* in_sizes, int n_in,
                              void* d_out, int out_size, void* d_ws, size_t ws_size,
                              hipStream_t stream) {
  (void)in_sizes; (void)n_in; (void)out_size; (void)ws_size;
  const float* x  = (const float*)d_in[0];
  const float* Wq = (const float*)d_in[1];
  const float* Wk = (const float*)d_in[2];
  const float* Wv = (const float*)d_in[3];
  const float* Wo = (const float*)d_in[4];
  const float* Pk = (const float*)d_in[5];
  const float* Pv = (const float*)d_in[6];

  ushort* wsu = (ushort*)d_ws;
  ushort* PkT    = wsu;                   // 8*256*4096
  ushort* PvT    = PkT + 8388608;
  ushort* WqT    = PvT + 8388608;         // 8*128*128
  ushort* WkT    = WqT + 131072;
  ushort* WvoT   = WkT + 131072;
  ushort* k_redb = WvoT + 131072;         // 64*256*128
  ushort* vo_redT = k_redb + 2097152;     // 64*128*256   (total ~42.5 MB)
  ushort* xT = (ushort*)d_out;            // 64*128*4096 bf16 = 67 MB, scratch;
                                          // k2 overwrites all of d_out afterwards

  k0_weights<<<dim3(NG), dim3(256), 0, stream>>>(Wq, Wk, Wv, Wo, WqT, WkT, WvoT);
  kt_x<<<dim3(64, 64), dim3(256), 0, stream>>>(x, xT);
  kt_p<<<dim3(64, 2, 8), dim3(256), 0, stream>>>(Pk, PkT);
  kt_p<<<dim3(64, 2, 8), dim3(256), 0, stream>>>(Pv, PvT);
  k1_mfma<<<dim3(4, 2, 64), dim3(256), 0, stream>>>(PkT, PvT, xT, WkT, WvoT,
                                                    k_redb, vo_redT);
  k2_attn<<<dim3(64, 64), dim3(512), 0, stream>>>(x, WqT, k_redb, vo_redT,
                                                  (float*)d_out);
}